// Round 11
// baseline (258.424 us; speedup 1.0000x reference)
//
#include <hip/hip_runtime.h>
#include <stdint.h>
#include <math.h>

typedef unsigned int u32;
typedef unsigned long long u64;

#define NBUCKET 16384   // radix = top 14 bits of order-preserving key
#define BSHIFT  18      // u >> 18 -> 14-bit bucket
#define HBINS 16512     // LDS histogram bins in k_finish (>= P+2)

__device__ __forceinline__ u32 f2key(float f){
  u32 b = __float_as_uint(f);
  return (b & 0x80000000u) ? ~b : (b | 0x80000000u);
}

// Fused: bucket histogram + P counts + D-table fill (4 phase-shifted copies).
__global__ void k_hist(const float* __restrict__ scores, const int* __restrict__ labels,
                       int B, int NC, u32* __restrict__ bhist, u32* __restrict__ Pcnt,
                       float* __restrict__ Dsh, int SD){
  int t = blockIdx.x*256 + threadIdx.x;
  if (t < 4*SD){
    int p = t / SD, y = t - p*SD;
    long long x = (long long)y + p;
    Dsh[t] = (x==0) ? 0.0f : (float)(1.0/log2(1.0 + (double)x));
  }
  if (t >= B*NC) return;
  int b = t / NC, c = t - (t/NC)*NC;
  float v = scores[t];
  int isPos = (labels[b] == c);
  u32 u = f2key(v);
  u32 bucket = u >> BSHIFT;
  int pi = c*2 + (isPos ? 0 : 1);   // part0=pos, part1=neg
  atomicAdd(&bhist[(size_t)pi*NBUCKET + bucket], 1u);
  if (isPos) atomicAdd(&Pcnt[c], 1u);
}

// Exclusive scan of 16384 bins per (class,part); 16 bins/thread; init cursors.
__global__ void k_scan(const u32* __restrict__ bhist, u32* __restrict__ bstart, u32* __restrict__ bcursor){
  __shared__ u32 sc[1024];
  int pi = blockIdx.x, tid = threadIdx.x;
  const u32* h = bhist + (size_t)pi*NBUCKET;
  u32 v[16]; u32 tot = 0u;
  #pragma unroll
  for (int k=0;k<16;k++){ v[k] = h[tid*16+k]; tot += v[k]; }
  sc[tid] = tot; __syncthreads();
  for (int off=1; off<1024; off<<=1){
    u32 t2 = (tid>=off) ? sc[tid-off] : 0u;
    __syncthreads();
    sc[tid] += t2;
    __syncthreads();
  }
  u32 run = sc[tid] - tot;  // exclusive prefix for this thread's 16 bins
  u32* bs = bstart  + (size_t)pi*(NBUCKET+1);
  u32* bc = bcursor + (size_t)pi*NBUCKET;
  #pragma unroll
  for (int k=0;k<16;k++){ bs[tid*16+k]=run; bc[tid*16+k]=run; run+=v[k]; }
  if (tid==1023) bs[NBUCKET]=run;
}

// Scatter packed keys (key<<32 | orig_index) into bucket-grouped order.
__global__ void k_scatter(const float* __restrict__ scores, const int* __restrict__ labels,
                          int B, int NC, u32* __restrict__ bcursor, u64* __restrict__ keyArr){
  int t = blockIdx.x*256 + threadIdx.x;
  if (t >= B*NC) return;
  int b = t / NC, c = t - (t/NC)*NC;
  float v = scores[t];
  int isPos = (labels[b] == c);
  u32 u = f2key(v);
  u32 bucket = u >> BSHIFT;
  int pi = c*2 + (isPos ? 0 : 1);
  u32 slot = atomicAdd(&bcursor[(size_t)pi*NBUCKET + bucket], 1u);
  keyArr[(size_t)pi*B + slot] = ((u64)u << 32) | (u32)b;
}

// Exact rank within bucket (deterministic via unique packed keys) -> sorted arrays.
__global__ void k_rank(const u64* __restrict__ keyArr, const u32* __restrict__ bstart,
                       const u32* __restrict__ Pcnt, int B,
                       float* __restrict__ sPos, float* __restrict__ sNeg){
  int pi = blockIdx.y; int c = pi >> 1; int part = pi & 1;
  u32 P = Pcnt[c];
  u32 cnt = part ? ((u32)B - P) : P;
  u32 t = blockIdx.x*256 + threadIdx.x;
  if (t >= cnt) return;
  const u64* ka = keyArr + (size_t)pi*B;
  u64 K = ka[t];
  u32 bucket = (u32)(K >> (32 + BSHIFT));
  const u32* bs = bstart + (size_t)pi*(NBUCKET+1);
  u32 lo = bs[bucket], hi = bs[bucket+1];
  u32 r = lo;
  for (u32 x=lo; x<hi; ++x) r += (ka[x] < K) ? 1u : 0u;
  u32 u = (u32)(K >> 32);
  u32 bits = (u & 0x80000000u) ? (u & 0x7fffffffu) : ~u;
  float val = __uint_as_float(bits);
  if (part == 0) sPos[(size_t)c*B + (P-1u-r)] = val;   // descending
  else           sNeg[(size_t)c*B + r]        = val;   // ascending
}

// Per-class: Cconst, scan-based suffix sums -> scaled coefficients A', B'.
__global__ void k_pre(const float* __restrict__ sPos, const u32* __restrict__ Pcnt,
                      const float* __restrict__ Dsh, int B, int strideAB,
                      float* __restrict__ Aarr, float* __restrict__ Barr,
                      double* __restrict__ Cconst){
  __shared__ double sd[1024];
  int c = blockIdx.x, tid = threadIdx.x;
  u32 P = Pcnt[c]; u32 N = (u32)B - P;
  if (P==0 || N==0){ if (tid==0) Cconst[c]=1.0; return; }

  double s=0.0;
  for (u32 i=1+tid; i<=P; i+=1024) s += (double)Dsh[i];   // copy 0 == plain Dtab
  sd[tid]=s; __syncthreads();
  for (int off=512; off>0; off>>=1){ if (tid<off) sd[tid]+=sd[tid+off]; __syncthreads(); }
  double Cc = sd[0];
  if (tid==0) Cconst[c]=Cc;
  __syncthreads();

  const float* sp = sPos + (size_t)c*B;

  double ts=0.0;
  for (u32 i=tid; i<P; i+=1024) ts += (double)sp[i];
  sd[tid]=ts; __syncthreads();
  for (int off=512; off>0; off>>=1){ if (tid<off) sd[tid]+=sd[tid+off]; __syncthreads(); }
  double totSp = sd[0];
  __syncthreads();

  double PN = (double)P*(double)N;
  double ca = -2.0*Cc/PN;
  double cb =  2.0*Cc/PN;
  float* A  = Aarr + (size_t)c*strideAB;
  float* Bc = Barr + (size_t)c*strideAB;

  double carry=0.0;
  int nch = ((int)P + 1023)/1024;
  for (int ch=0; ch<nch; ++ch){
    int x = ch*1024 + tid;
    double v = (x < (int)P) ? (double)sp[x] : 0.0;
    sd[tid]=v; __syncthreads();
    for (int off2=1; off2<1024; off2<<=1){
      double t2 = (tid>=off2) ? sd[tid-off2] : 0.0;
      __syncthreads();
      sd[tid]+=t2;
      __syncthreads();
    }
    if (x < (int)P){
      double excl = sd[tid] - v + carry;      // sum sp[0..x-1]
      double Sl = totSp - excl;               // sum_{k=x}^{P-1} sp[k]
      A[x]  = (float)(ca*Sl);
      Bc[x] = (float)(cb*(double)(P-(u32)x));
    }
    carry += sd[1023];
    __syncthreads();
  }
  if (tid==0){ A[P]=0.0f; Bc[P]=0.0f; }
}

// R9 k_main + per-block bracket: waves 0-1 compute exact leftmost-argmax
// anchors at m=base and m=base+255 (R8-proven code) -> optL[2] in LDS; the
// proven R9 vectorized scan (stride-4 m, phase-shifted-D float4, global A/B)
// then runs over [LO&~3, HI] only. Narrow window -> A/B/D L1-resident.
__global__ void k_main(const float* __restrict__ sNeg, const u32* __restrict__ Pcnt,
                       const float* __restrict__ Dsh, int SD,
                       const float* __restrict__ Aarr, const float* __restrict__ Barr,
                       int B, int strideAB,
                       u32* __restrict__ optArr, double* __restrict__ partials){
  __shared__ u32 optL[2];
  __shared__ double l1[4], l2[4];
  int c = blockIdx.y;
  u32 P = Pcnt[c]; u32 N = (u32)B - P;
  int base = blockIdx.x*256;
  int w    = threadIdx.x >> 6;
  int lane = threadIdx.x & 63;
  const float* A  = Aarr + (size_t)c*strideAB;
  const float* Bc = Barr + (size_t)c*strideAB;
  const float* sn = sNeg + (size_t)c*B;
  bool classValid = (P>0u && N>0u);
  bool blockValid = classValid && (base < (int)N);
  int total = (int)P + 1;

  // ---- phase 1: two exact anchors (waves 0 and 1) ----
  if (blockValid && w < 2){
    int ma = (w == 0) ? base : min(base + 255, (int)N - 1);
    float sm = sn[ma];
    const float* D0 = Dsh + ma + 1;
    float best = -3.402823466e38f; u32 bj = 0xFFFFFFFFu;
    for (int j = lane; j < total; j += 64){
      float f = fmaf(Bc[j], sm, A[j]) + D0[j];
      if (f > best){ best = f; bj = (u32)j; }   // leftmost within lane subset
    }
    u64 key = (bj != 0xFFFFFFFFu)
            ? (((u64)f2key(best + 0.0f) << 32) | (u32)(~bj)) : 0ull;
    for (int off = 32; off > 0; off >>= 1){
      u64 o = __shfl_xor(key, off);
      key = (o > key) ? o : key;                // max f; tie -> smaller j
    }
    if (lane == 0) optL[w] = ~(u32)key;
  }
  __syncthreads();

  // ---- phase 2: bracketed vectorized scan (R9 loop, restricted bounds) ----
  double s1=0.0, s2=0.0;
  int m = base + w + 4*lane;                    // R9 stride-4 mapping
  if (blockValid && m < (int)N){
    int LO = (int)optL[0];
    int HI = (int)optL[1];
    if (HI < LO) HI = LO;                       // fp-monotonicity safety
    int LO4 = LO & ~3;                          // aligned scan start
    float sm = sn[m];
    int ph = (m+1) & 3;                               // wave-uniform
    const float* Dp = Dsh + (size_t)ph*SD + (m+1-ph); // Dp[j] 16B-aligned at j%4==0
    float best = -3.402823466e38f; u32 bj = (u32)LO4;
    int j = LO4;
    for (; j + 3 <= HI; j += 4){
      float4 d = *(const float4*)(Dp + j);
      float4 a = *(const float4*)(A + j);
      float4 b = *(const float4*)(Bc + j);
      float f0 = fmaf(b.x, sm, a.x) + d.x;
      float f1 = fmaf(b.y, sm, a.y) + d.y;
      float f2 = fmaf(b.z, sm, a.z) + d.z;
      float f3 = fmaf(b.w, sm, a.w) + d.w;
      if (f0 > best){ best=f0; bj=(u32)j; }
      if (f1 > best){ best=f1; bj=(u32)(j+1); }
      if (f2 > best){ best=f2; bj=(u32)(j+2); }
      if (f3 > best){ best=f3; bj=(u32)(j+3); }
    }
    for (; j <= HI; ++j){
      float f = fmaf(Bc[j], sm, A[j]) + Dp[j];
      if (f > best){ best=f; bj=(u32)j; }
    }
    u32 opt = bj + 1u;
    optArr[(size_t)c*B + m] = opt;        // plain coalesced store, no atomic
    s1 = (double)sm;
    s2 = (double)sm * (double)opt;
  }
  for (int off=32; off>0; off>>=1){
    s1 += __shfl_down(s1, off);
    s2 += __shfl_down(s2, off);
  }
  if (lane==0){ l1[w]=s1; l2[w]=s2; }
  __syncthreads();
  if (threadIdx.x==0){
    double* p = partials + ((size_t)c*gridDim.x + blockIdx.x)*2;
    p[0] = l1[0]+l1[1]+l1[2]+l1[3];
    p[1] = l2[0]+l2[1]+l2[2]+l2[3];
  }
}

// Per-class finish: ORDER-AGNOSTIC r_plus via per-class LDS histogram of optArr
// + chunked prefix scan; last-block-done final reduction writes out[0].
__global__ void k_finish(const float* __restrict__ sPos, const u32* __restrict__ Pcnt,
                         const u32* __restrict__ optArr, const float* __restrict__ Dsh,
                         const double* __restrict__ Cconst, const double* __restrict__ partials,
                         int B, int nblkM, int NC,
                         u64* __restrict__ classLoss, u32* __restrict__ doneCount,
                         float* __restrict__ out){
  __shared__ u32 hbins[HBINS];
  __shared__ u32 sc[1024];
  __shared__ double rd[1024];
  int c = blockIdx.x, tid = threadIdx.x;
  u32 P = Pcnt[c]; u32 N = (u32)B - P;
  double myLoss = 0.0;
  if (P!=0 && N!=0){
    const u32* oa = optArr + (size_t)c*B;
    const float* sp = sPos + (size_t)c*B;
    double sumD=0.0, sumSpr=0.0, sumSp=0.0;
    if ((int)P + 2 <= HBINS){
      for (int i = tid; i < (int)P + 2; i += 1024) hbins[i] = 0u;
      __syncthreads();
      for (int m2 = tid; m2 < (int)N; m2 += 1024)
        atomicAdd(&hbins[oa[m2]], 1u);             // LDS atomic
      __syncthreads();
      u32 carry=0u;
      int nch = ((int)P + 1023)/1024;
      for (int ch=0; ch<nch; ++ch){
        int x = ch*1024 + tid;
        u32 v = (x < (int)P) ? hbins[x+1] : 0u;
        sc[tid]=v; __syncthreads();
        for (int off=1; off<1024; off<<=1){
          u32 t2 = (tid>=off) ? sc[tid-off] : 0u;
          __syncthreads();
          sc[tid] += t2;
          __syncthreads();
        }
        u32 cum = sc[tid] + carry;
        if (x < (int)P){
          u32 r = 1u + cum;
          float spv = sp[x];
          sumD   += (double)Dsh[x + r];
          sumSpr += (double)spv * (double)r;
          sumSp  += (double)spv;
        }
        carry += sc[1023];
        __syncthreads();
      }
    } else {
      for (int x = tid; x < (int)P; x += 1024){
        u32 target = (u32)x + 1u, cnt2 = 0u;
        for (u32 m2 = 0; m2 < N; ++m2) cnt2 += (oa[m2] <= target) ? 1u : 0u;
        u32 r = 1u + cnt2;
        float spv = sp[x];
        sumD   += (double)Dsh[x + r];
        sumSpr += (double)spv * (double)r;
        sumSp  += (double)spv;
      }
    }
    rd[tid]=sumD; __syncthreads();
    for (int off=512; off>0; off>>=1){ if (tid<off) rd[tid]+=rd[tid+off]; __syncthreads(); }
    double totD = rd[0]; __syncthreads();
    rd[tid]=sumSpr; __syncthreads();
    for (int off=512; off>0; off>>=1){ if (tid<off) rd[tid]+=rd[tid+off]; __syncthreads(); }
    double totSpr = rd[0]; __syncthreads();
    rd[tid]=sumSp; __syncthreads();
    for (int off=512; off>0; off>>=1){ if (tid<off) rd[tid]+=rd[tid+off]; __syncthreads(); }
    double totSp = rd[0];
    if (tid==0){
      double S1=0.0, S2=0.0;
      const double* pp = partials + (size_t)c*nblkM*2;
      for (int b=0;b<nblkM;b++){ S1+=pp[2*b]; S2+=pp[2*b+1]; }
      double Cc = Cconst[c];
      double Delta = 1.0 - totD/Cc;
      double Fp    = (double)(N+2u)*totSp - 2.0*totSpr;   // sum s_plus*c_plus
      double Fm    = (double)(P+2u)*S1   - 2.0*S2;        // sum s_minus*c_minus
      double Fstar = (double)N*totSp - (double)P*S1;
      myLoss = Delta + (Fp + Fm - Fstar)/((double)P*(double)N);
    }
  }
  if (tid==0){
    atomicExch(&classLoss[c], (u64)__double_as_longlong(myLoss));
    __threadfence();
    u32 old = atomicAdd(doneCount, 1u);
    if (old == (u32)gridDim.x - 1u){
      __threadfence();
      double s=0.0;
      for (int cc=0; cc<NC; ++cc){
        u64 bits = atomicAdd(&classLoss[cc], 0ull);  // coherent read
        s += __longlong_as_double((long long)bits);
      }
      out[0] = (float)(s/(double)NC);
    }
  }
}

extern "C" void kernel_launch(void* const* d_in, const int* in_sizes, int n_in,
                              void* d_out, int out_size, void* d_ws, size_t ws_size,
                              hipStream_t stream) {
  const float* scores = (const float*)d_in[0];
  const int*   labels = (const int*)d_in[1];
  int B  = in_sizes[1];
  int NC = in_sizes[0] / in_sizes[1];
  float* out = (float*)d_out;

  int SD = B + 8;            // per-copy stride of shifted D tables
  int strideAB = B + 8;      // per-class stride of A/B
  int nblkM = (B + 255)/256; // k_main blocks per class

  char* ws = (char*)d_ws;
  size_t off = 0;
  auto alloc = [&](size_t bytes)->char* {
    char* p = ws + off;
    off = (off + bytes + 255) & ~(size_t)255;
    return p;
  };
  float* Dsh = (float*)alloc((size_t)4*SD*4);
  // ---- zeroed region (must stay contiguous) ----
  char* zbeg = ws + off;
  u32* bhist     = (u32*)alloc((size_t)NC*2*NBUCKET*4);
  u32* Pcnt      = (u32*)alloc((size_t)NC*4);
  u32* doneCount = (u32*)alloc(4);
  char* zend = ws + off;
  // ----------------------------------------------
  u32* bstart    = (u32*)alloc((size_t)NC*2*(NBUCKET+1)*4);
  u32* bcursor   = (u32*)alloc((size_t)NC*2*NBUCKET*4);
  u64* keyArr    = (u64*)alloc((size_t)NC*2*B*8);
  float* sPos    = (float*)alloc((size_t)NC*B*4);
  float* sNeg    = (float*)alloc((size_t)NC*B*4);
  float* Aarr    = (float*)alloc((size_t)NC*strideAB*4);
  float* Barr    = (float*)alloc((size_t)NC*strideAB*4);
  double* Cconst = (double*)alloc((size_t)NC*8);
  u32* optArr    = (u32*)alloc((size_t)NC*B*4);
  double* partials  = (double*)alloc((size_t)NC*nblkM*2*8);
  u64* classLoss    = (u64*)alloc((size_t)NC*8);

  hipMemsetAsync(zbeg, 0, (size_t)(zend - zbeg), stream);

  k_hist<<<(B*NC+255)/256, 256, 0, stream>>>(scores, labels, B, NC, bhist, Pcnt, Dsh, SD);
  k_scan<<<NC*2, 1024, 0, stream>>>(bhist, bstart, bcursor);
  k_scatter<<<(B*NC+255)/256, 256, 0, stream>>>(scores, labels, B, NC, bcursor, keyArr);
  k_rank<<<dim3((B+255)/256, NC*2), 256, 0, stream>>>(keyArr, bstart, Pcnt, B, sPos, sNeg);
  k_pre<<<NC, 1024, 0, stream>>>(sPos, Pcnt, Dsh, B, strideAB, Aarr, Barr, Cconst);
  k_main<<<dim3(nblkM, NC), 256, 0, stream>>>(sNeg, Pcnt, Dsh, SD, Aarr, Barr,
                                              B, strideAB, optArr, partials);
  k_finish<<<NC, 1024, 0, stream>>>(sPos, Pcnt, optArr, Dsh, Cconst, partials, B, nblkM, NC,
                                    classLoss, doneCount, out);
}

// Round 12
// 227.281 us; speedup vs baseline: 1.1370x; 1.1370x over previous
//
#include <hip/hip_runtime.h>
#include <stdint.h>
#include <math.h>

typedef unsigned int u32;
typedef unsigned long long u64;

#define NBUCKET 16384   // radix = top 14 bits of order-preserving key
#define BSHIFT  18      // u >> 18 -> 14-bit bucket
#define HBINS 16512     // LDS histogram bins in k_finish (>= P+2)
#define SMAX 2560       // LDS floats per A/B array in k_main (fast path: P+1 <= SMAX-4)

__device__ __forceinline__ u32 f2key(float f){
  u32 b = __float_as_uint(f);
  return (b & 0x80000000u) ? ~b : (b | 0x80000000u);
}

// ---- wave-shfl block primitives (1024 threads = 16 waves) ----
// block reduce (sum) -> broadcast; ds must hold >=17 doubles; 2 barriers + tail barrier
__device__ __forceinline__ double blk_reduce_d(double v, int tid, double* ds){
  int lane = tid & 63, wid = tid >> 6;
  for (int off=32; off>0; off>>=1) v += __shfl_down(v, off);
  if (lane==0) ds[wid] = v;
  __syncthreads();
  if (tid < 64){
    double t = (tid<16)? ds[tid] : 0.0;
    for (int off=8; off>0; off>>=1) t += __shfl_down(t, off);
    if (tid==0) ds[16] = t;
  }
  __syncthreads();
  double r = ds[16];
  __syncthreads();           // protect ds for immediate reuse
  return r;
}

// block inclusive scan; ds >=17 doubles; after return ds[15] == block total
// (caller must __syncthreads() after consuming ds[15], before next use of ds)
__device__ __forceinline__ double blk_scan_incl_d(double v, int tid, double* ds){
  int lane = tid & 63, wid = tid >> 6;
  double sv = v;
  for (int off=1; off<64; off<<=1){
    double o = __shfl_up(sv, off);
    if (lane >= off) sv += o;
  }
  if (lane==63) ds[wid] = sv;
  __syncthreads();
  if (tid < 64){
    double w = (tid<16)? ds[tid] : 0.0;
    for (int off=1; off<16; off<<=1){
      double o = __shfl_up(w, off);
      if (tid >= off) w += o;
    }
    if (tid<16) ds[tid] = w;
  }
  __syncthreads();
  double add = (wid>0)? ds[wid-1] : 0.0;
  return sv + add;
}

// u32 versions
__device__ __forceinline__ u32 blk_scan_incl_u32(u32 v, int tid, u32* ws){
  int lane = tid & 63, wid = tid >> 6;
  u32 sv = v;
  for (int off=1; off<64; off<<=1){
    u32 o = __shfl_up(sv, off);
    if (lane >= off) sv += o;
  }
  if (lane==63) ws[wid] = sv;
  __syncthreads();
  if (tid < 64){
    u32 w = (tid<16)? ws[tid] : 0u;
    for (int off=1; off<16; off<<=1){
      u32 o = __shfl_up(w, off);
      if (tid >= off) w += o;
    }
    if (tid<16) ws[tid] = w;
  }
  __syncthreads();
  u32 add = (wid>0)? ws[wid-1] : 0u;
  return sv + add;
}

// Fused: bucket histogram + P counts + D-table fill (4 phase-shifted copies).
__global__ void k_hist(const float* __restrict__ scores, const int* __restrict__ labels,
                       int B, int NC, u32* __restrict__ bhist, u32* __restrict__ Pcnt,
                       float* __restrict__ Dsh, int SD){
  int t = blockIdx.x*256 + threadIdx.x;
  if (t < 4*SD){
    int p = t / SD, y = t - p*SD;
    long long x = (long long)y + p;
    Dsh[t] = (x==0) ? 0.0f : (float)(1.0/log2(1.0 + (double)x));
  }
  if (t >= B*NC) return;
  int b = t / NC, c = t - (t/NC)*NC;
  float v = scores[t];
  int isPos = (labels[b] == c);
  u32 u = f2key(v);
  u32 bucket = u >> BSHIFT;
  int pi = c*2 + (isPos ? 0 : 1);   // part0=pos, part1=neg
  atomicAdd(&bhist[(size_t)pi*NBUCKET + bucket], 1u);
  if (isPos) atomicAdd(&Pcnt[c], 1u);
}

// Exclusive scan of 16384 bins per (class,part); 16 bins/thread; shfl scan.
__global__ void k_scan(const u32* __restrict__ bhist, u32* __restrict__ bstart, u32* __restrict__ bcursor){
  __shared__ u32 ws[17];
  int pi = blockIdx.x, tid = threadIdx.x;
  const u32* h = bhist + (size_t)pi*NBUCKET;
  u32 v[16]; u32 tot = 0u;
  #pragma unroll
  for (int k=0;k<16;k++){ v[k] = h[tid*16+k]; tot += v[k]; }
  u32 incl = blk_scan_incl_u32(tot, tid, ws);
  u32 run = incl - tot;  // exclusive prefix for this thread's 16 bins
  u32* bs = bstart  + (size_t)pi*(NBUCKET+1);
  u32* bc = bcursor + (size_t)pi*NBUCKET;
  #pragma unroll
  for (int k=0;k<16;k++){ bs[tid*16+k]=run; bc[tid*16+k]=run; run+=v[k]; }
  if (tid==1023) bs[NBUCKET]=incl;
}

// Scatter packed keys (key<<32 | orig_index) into bucket-grouped order.
__global__ void k_scatter(const float* __restrict__ scores, const int* __restrict__ labels,
                          int B, int NC, u32* __restrict__ bcursor, u64* __restrict__ keyArr){
  int t = blockIdx.x*256 + threadIdx.x;
  if (t >= B*NC) return;
  int b = t / NC, c = t - (t/NC)*NC;
  float v = scores[t];
  int isPos = (labels[b] == c);
  u32 u = f2key(v);
  u32 bucket = u >> BSHIFT;
  int pi = c*2 + (isPos ? 0 : 1);
  u32 slot = atomicAdd(&bcursor[(size_t)pi*NBUCKET + bucket], 1u);
  keyArr[(size_t)pi*B + slot] = ((u64)u << 32) | (u32)b;
}

// Exact rank within bucket (deterministic via unique packed keys) -> sorted arrays.
__global__ void k_rank(const u64* __restrict__ keyArr, const u32* __restrict__ bstart,
                       const u32* __restrict__ Pcnt, int B,
                       float* __restrict__ sPos, float* __restrict__ sNeg){
  int pi = blockIdx.y; int c = pi >> 1; int part = pi & 1;
  u32 P = Pcnt[c];
  u32 cnt = part ? ((u32)B - P) : P;
  u32 t = blockIdx.x*256 + threadIdx.x;
  if (t >= cnt) return;
  const u64* ka = keyArr + (size_t)pi*B;
  u64 K = ka[t];
  u32 bucket = (u32)(K >> (32 + BSHIFT));
  const u32* bs = bstart + (size_t)pi*(NBUCKET+1);
  u32 lo = bs[bucket], hi = bs[bucket+1];
  u32 r = lo;
  for (u32 x=lo; x<hi; ++x) r += (ka[x] < K) ? 1u : 0u;
  u32 u = (u32)(K >> 32);
  u32 bits = (u & 0x80000000u) ? (u & 0x7fffffffu) : ~u;
  float val = __uint_as_float(bits);
  if (part == 0) sPos[(size_t)c*B + (P-1u-r)] = val;   // descending
  else           sNeg[(size_t)c*B + r]        = val;   // ascending
}

// Per-class: Cconst, shfl-scan-based suffix sums -> scaled coefficients A', B'.
__global__ void k_pre(const float* __restrict__ sPos, const u32* __restrict__ Pcnt,
                      const float* __restrict__ Dsh, int B, int strideAB,
                      float* __restrict__ Aarr, float* __restrict__ Barr,
                      double* __restrict__ Cconst){
  __shared__ double ds[17];
  int c = blockIdx.x, tid = threadIdx.x;
  u32 P = Pcnt[c]; u32 N = (u32)B - P;
  if (P==0 || N==0){ if (tid==0) Cconst[c]=1.0; return; }

  double s=0.0;
  for (u32 i=1+tid; i<=P; i+=1024) s += (double)Dsh[i];   // copy 0 == plain Dtab
  double Cc = blk_reduce_d(s, tid, ds);
  if (tid==0) Cconst[c]=Cc;

  const float* sp = sPos + (size_t)c*B;
  double ts=0.0;
  for (u32 i=tid; i<P; i+=1024) ts += (double)sp[i];
  double totSp = blk_reduce_d(ts, tid, ds);

  double PN = (double)P*(double)N;
  double ca = -2.0*Cc/PN;
  double cb =  2.0*Cc/PN;
  float* A  = Aarr + (size_t)c*strideAB;
  float* Bc = Barr + (size_t)c*strideAB;

  double carry=0.0;
  int nch = ((int)P + 1023)/1024;
  for (int ch=0; ch<nch; ++ch){
    int x = ch*1024 + tid;
    double v = (x < (int)P) ? (double)sp[x] : 0.0;
    double incl = blk_scan_incl_d(v, tid, ds);
    if (x < (int)P){
      double excl = incl - v + carry;         // sum sp[0..x-1]
      double Sl = totSp - excl;               // sum_{k=x}^{P-1} sp[k]
      A[x]  = (float)(ca*Sl);
      Bc[x] = (float)(cb*(double)(P-(u32)x));
    }
    carry += ds[15];                          // block total of this chunk
    __syncthreads();                          // protect ds for next chunk
  }
  if (tid==0){ A[P]=0.0f; Bc[P]=0.0f; }
}

// Brute-force argmax (R9, proven 72us / absmax 0.0): A/B staged in LDS,
// stride-4 m-assignment, phase-shifted-D float4 loads.
__global__ void k_main(const float* __restrict__ sNeg, const u32* __restrict__ Pcnt,
                       const float* __restrict__ Dsh, int SD,
                       const float* __restrict__ Aarr, const float* __restrict__ Barr,
                       int B, int strideAB,
                       u32* __restrict__ optArr, double* __restrict__ partials){
  __shared__ float sA[SMAX], sB[SMAX];
  __shared__ double l1[4], l2[4];
  int c = blockIdx.y;
  u32 P = Pcnt[c]; u32 N = (u32)B - P;
  int w    = threadIdx.x >> 6;
  int lane = threadIdx.x & 63;
  int m = blockIdx.x*256 + w + 4*lane;
  const float* A  = Aarr + (size_t)c*strideAB;
  const float* Bc = Barr + (size_t)c*strideAB;
  bool classValid = (P>0u && N>0u);
  int total = (int)P + 1;
  int nv = (total + 3) >> 2;                 // float4 count covering [0, total)
  bool useLds = (total <= SMAX - 4);
  if (classValid && useLds){
    const float4* A4 = (const float4*)A;
    const float4* B4 = (const float4*)Bc;
    float4* sA4 = (float4*)sA;
    float4* sB4 = (float4*)sB;
    for (int i = threadIdx.x; i <= nv; i += 256){ sA4[i] = A4[i]; sB4[i] = B4[i]; }
  }
  __syncthreads();

  double s1=0.0, s2=0.0;
  if (classValid && m < (int)N){
    float sm = sNeg[(size_t)c*B + m];
    int ph = (m+1) & 3;                               // wave-uniform (m stride 4)
    const float* Dp = Dsh + (size_t)ph*SD + (m+1-ph); // Dp[j]=D(m+1+j); 16B-aligned at j%4==0
    int jmax4 = total & ~3;
    float best = -3.402823466e38f; u32 bj = 0u;
    int j = 0;
    if (useLds){
      #pragma unroll 2
      for (; j < jmax4; j += 4){
        float4 d = *(const float4*)(Dp + j);
        float4 a = *(const float4*)(sA + j);
        float4 b = *(const float4*)(sB + j);
        float f0 = fmaf(b.x, sm, a.x) + d.x;
        float f1 = fmaf(b.y, sm, a.y) + d.y;
        float f2 = fmaf(b.z, sm, a.z) + d.z;
        float f3 = fmaf(b.w, sm, a.w) + d.w;
        if (f0 > best){ best=f0; bj=(u32)j; }
        if (f1 > best){ best=f1; bj=(u32)(j+1); }
        if (f2 > best){ best=f2; bj=(u32)(j+2); }
        if (f3 > best){ best=f3; bj=(u32)(j+3); }
      }
      for (; j < total; ++j){
        float f = fmaf(sB[j], sm, sA[j]) + Dp[j];
        if (f > best){ best=f; bj=(u32)j; }
      }
    } else {
      #pragma unroll 2
      for (; j < jmax4; j += 4){
        float4 d = *(const float4*)(Dp + j);
        float4 a = *(const float4*)(A + j);
        float4 b = *(const float4*)(Bc + j);
        float f0 = fmaf(b.x, sm, a.x) + d.x;
        float f1 = fmaf(b.y, sm, a.y) + d.y;
        float f2 = fmaf(b.z, sm, a.z) + d.z;
        float f3 = fmaf(b.w, sm, a.w) + d.w;
        if (f0 > best){ best=f0; bj=(u32)j; }
        if (f1 > best){ best=f1; bj=(u32)(j+1); }
        if (f2 > best){ best=f2; bj=(u32)(j+2); }
        if (f3 > best){ best=f3; bj=(u32)(j+3); }
      }
      for (; j < total; ++j){
        float f = fmaf(Bc[j], sm, A[j]) + Dp[j];
        if (f > best){ best=f; bj=(u32)j; }
      }
    }
    u32 opt = bj + 1u;
    optArr[(size_t)c*B + m] = opt;        // plain coalesced store, no atomic
    s1 = (double)sm;
    s2 = (double)sm * (double)opt;
  }
  for (int off=32; off>0; off>>=1){
    s1 += __shfl_down(s1, off);
    s2 += __shfl_down(s2, off);
  }
  if (lane==0){ l1[w]=s1; l2[w]=s2; }
  __syncthreads();
  if (threadIdx.x==0){
    double* p = partials + ((size_t)c*gridDim.x + blockIdx.x)*2;
    p[0] = l1[0]+l1[1]+l1[2]+l1[3];
    p[1] = l2[0]+l2[1]+l2[2]+l2[3];
  }
}

// Per-class finish: ORDER-AGNOSTIC r_plus via per-class LDS histogram of optArr
// + shfl-based chunked scan; shfl reductions; last-block-done writes out[0].
__global__ void k_finish(const float* __restrict__ sPos, const u32* __restrict__ Pcnt,
                         const u32* __restrict__ optArr, const float* __restrict__ Dsh,
                         const double* __restrict__ Cconst, const double* __restrict__ partials,
                         int B, int nblkM, int NC,
                         u64* __restrict__ classLoss, u32* __restrict__ doneCount,
                         float* __restrict__ out){
  __shared__ u32 hbins[HBINS];
  __shared__ u32 ws[17];
  __shared__ double ds[17];
  int c = blockIdx.x, tid = threadIdx.x;
  u32 P = Pcnt[c]; u32 N = (u32)B - P;
  double myLoss = 0.0;
  if (P!=0 && N!=0){
    const u32* oa = optArr + (size_t)c*B;
    const float* sp = sPos + (size_t)c*B;
    double sumD=0.0, sumSpr=0.0, sumSp=0.0;
    if ((int)P + 2 <= HBINS){
      for (int i = tid; i < (int)P + 2; i += 1024) hbins[i] = 0u;
      __syncthreads();
      for (int m2 = tid; m2 < (int)N; m2 += 1024)
        atomicAdd(&hbins[oa[m2]], 1u);             // LDS atomic (~9/bin avg)
      __syncthreads();
      u32 carry=0u;
      int nch = ((int)P + 1023)/1024;
      for (int ch=0; ch<nch; ++ch){
        int x = ch*1024 + tid;
        u32 v = (x < (int)P) ? hbins[x+1] : 0u;
        u32 incl = blk_scan_incl_u32(v, tid, ws);
        u32 cum = incl + carry;
        if (x < (int)P){
          u32 r = 1u + cum;
          float spv = sp[x];
          sumD   += (double)Dsh[x + r];
          sumSpr += (double)spv * (double)r;
          sumSp  += (double)spv;
        }
        carry += ws[15];                           // chunk total
        __syncthreads();
      }
    } else {
      for (int x = tid; x < (int)P; x += 1024){
        u32 target = (u32)x + 1u, cnt2 = 0u;
        for (u32 m2 = 0; m2 < N; ++m2) cnt2 += (oa[m2] <= target) ? 1u : 0u;
        u32 r = 1u + cnt2;
        float spv = sp[x];
        sumD   += (double)Dsh[x + r];
        sumSpr += (double)spv * (double)r;
        sumSp  += (double)spv;
      }
    }
    double totD   = blk_reduce_d(sumD,   tid, ds);
    double totSpr = blk_reduce_d(sumSpr, tid, ds);
    double totSp  = blk_reduce_d(sumSp,  tid, ds);
    if (tid==0){
      double S1=0.0, S2=0.0;
      const double* pp = partials + (size_t)c*nblkM*2;
      for (int b=0;b<nblkM;b++){ S1+=pp[2*b]; S2+=pp[2*b+1]; }
      double Cc = Cconst[c];
      double Delta = 1.0 - totD/Cc;
      double Fp    = (double)(N+2u)*totSp - 2.0*totSpr;   // sum s_plus*c_plus
      double Fm    = (double)(P+2u)*S1   - 2.0*S2;        // sum s_minus*c_minus
      double Fstar = (double)N*totSp - (double)P*S1;
      myLoss = Delta + (Fp + Fm - Fstar)/((double)P*(double)N);
    }
  }
  if (tid==0){
    atomicExch(&classLoss[c], (u64)__double_as_longlong(myLoss));
    __threadfence();
    u32 old = atomicAdd(doneCount, 1u);
    if (old == (u32)gridDim.x - 1u){
      __threadfence();
      double s=0.0;
      for (int cc=0; cc<NC; ++cc){
        u64 bits = atomicAdd(&classLoss[cc], 0ull);  // coherent read
        s += __longlong_as_double((long long)bits);
      }
      out[0] = (float)(s/(double)NC);
    }
  }
}

extern "C" void kernel_launch(void* const* d_in, const int* in_sizes, int n_in,
                              void* d_out, int out_size, void* d_ws, size_t ws_size,
                              hipStream_t stream) {
  const float* scores = (const float*)d_in[0];
  const int*   labels = (const int*)d_in[1];
  int B  = in_sizes[1];
  int NC = in_sizes[0] / in_sizes[1];
  float* out = (float*)d_out;

  int SD = B + 8;            // per-copy stride of shifted D tables
  int strideAB = B + 8;      // per-class stride of A/B
  int nblkM = (B + 255)/256; // k_main blocks per class

  char* ws = (char*)d_ws;
  size_t off = 0;
  auto alloc = [&](size_t bytes)->char* {
    char* p = ws + off;
    off = (off + bytes + 255) & ~(size_t)255;
    return p;
  };
  float* Dsh = (float*)alloc((size_t)4*SD*4);
  // ---- zeroed region (must stay contiguous) ----
  char* zbeg = ws + off;
  u32* bhist     = (u32*)alloc((size_t)NC*2*NBUCKET*4);
  u32* Pcnt      = (u32*)alloc((size_t)NC*4);
  u32* doneCount = (u32*)alloc(4);
  char* zend = ws + off;
  // ----------------------------------------------
  u32* bstart    = (u32*)alloc((size_t)NC*2*(NBUCKET+1)*4);
  u32* bcursor   = (u32*)alloc((size_t)NC*2*NBUCKET*4);
  u64* keyArr    = (u64*)alloc((size_t)NC*2*B*8);
  float* sPos    = (float*)alloc((size_t)NC*B*4);
  float* sNeg    = (float*)alloc((size_t)NC*B*4);
  float* Aarr    = (float*)alloc((size_t)NC*strideAB*4);
  float* Barr    = (float*)alloc((size_t)NC*strideAB*4);
  double* Cconst = (double*)alloc((size_t)NC*8);
  u32* optArr    = (u32*)alloc((size_t)NC*B*4);
  double* partials  = (double*)alloc((size_t)NC*nblkM*2*8);
  u64* classLoss    = (u64*)alloc((size_t)NC*8);

  hipMemsetAsync(zbeg, 0, (size_t)(zend - zbeg), stream);

  k_hist<<<(B*NC+255)/256, 256, 0, stream>>>(scores, labels, B, NC, bhist, Pcnt, Dsh, SD);
  k_scan<<<NC*2, 1024, 0, stream>>>(bhist, bstart, bcursor);
  k_scatter<<<(B*NC+255)/256, 256, 0, stream>>>(scores, labels, B, NC, bcursor, keyArr);
  k_rank<<<dim3((B+255)/256, NC*2), 256, 0, stream>>>(keyArr, bstart, Pcnt, B, sPos, sNeg);
  k_pre<<<NC, 1024, 0, stream>>>(sPos, Pcnt, Dsh, B, strideAB, Aarr, Barr, Cconst);
  k_main<<<dim3(nblkM, NC), 256, 0, stream>>>(sNeg, Pcnt, Dsh, SD, Aarr, Barr,
                                              B, strideAB, optArr, partials);
  k_finish<<<NC, 1024, 0, stream>>>(sPos, Pcnt, optArr, Dsh, Cconst, partials, B, nblkM, NC,
                                    classLoss, doneCount, out);
}

// Round 13
// 223.063 us; speedup vs baseline: 1.1585x; 1.0189x over previous
//
#include <hip/hip_runtime.h>
#include <stdint.h>
#include <math.h>

typedef unsigned int u32;
typedef unsigned long long u64;

#define NBUCKET 16384   // radix = top 14 bits of order-preserving key
#define BSHIFT  18      // u >> 18 -> 14-bit bucket
#define HBINS 16512     // LDS histogram bins in k_finish (>= P+2)
#define CHK 2048        // j-chunk (LDS floats per A/B buffer) in k_main

__device__ __forceinline__ u32 f2key(float f){
  u32 b = __float_as_uint(f);
  return (b & 0x80000000u) ? ~b : (b | 0x80000000u);
}

// ---- 1024-thread (16-wave) primitives (proven R12) ----
__device__ __forceinline__ double blk_reduce_d(double v, int tid, double* ds){
  int lane = tid & 63, wid = tid >> 6;
  for (int off=32; off>0; off>>=1) v += __shfl_down(v, off);
  if (lane==0) ds[wid] = v;
  __syncthreads();
  if (tid < 64){
    double t = (tid<16)? ds[tid] : 0.0;
    for (int off=8; off>0; off>>=1) t += __shfl_down(t, off);
    if (tid==0) ds[16] = t;
  }
  __syncthreads();
  double r = ds[16];
  __syncthreads();
  return r;
}

__device__ __forceinline__ u32 blk_scan_incl_u32(u32 v, int tid, u32* ws){
  int lane = tid & 63, wid = tid >> 6;
  u32 sv = v;
  for (int off=1; off<64; off<<=1){
    u32 o = __shfl_up(sv, off);
    if (lane >= off) sv += o;
  }
  if (lane==63) ws[wid] = sv;
  __syncthreads();
  if (tid < 64){
    u32 w = (tid<16)? ws[tid] : 0u;
    for (int off=1; off<16; off<<=1){
      u32 o = __shfl_up(w, off);
      if (tid >= off) w += o;
    }
    if (tid<16) ws[tid] = w;
  }
  __syncthreads();
  u32 add = (wid>0)? ws[wid-1] : 0u;
  return sv + add;
}

// ---- 256-thread (4-wave) primitives for k_main ----
__device__ __forceinline__ double blk4_reduce_d(double v, int tid, double* ds){ // ds >= 5
  int lane = tid & 63, wid = tid >> 6;
  for (int off=32; off>0; off>>=1) v += __shfl_down(v, off);
  if (lane==0) ds[wid] = v;
  __syncthreads();
  if (tid==0) ds[4] = ds[0]+ds[1]+ds[2]+ds[3];
  __syncthreads();
  double r = ds[4];
  __syncthreads();
  return r;
}

// inclusive scan; after return ds[3] == block total (caller barriers before reuse)
__device__ __forceinline__ double blk4_scan_incl_d(double v, int tid, double* ds){
  int lane = tid & 63, wid = tid >> 6;
  double sv = v;
  for (int off=1; off<64; off<<=1){
    double o = __shfl_up(sv, off);
    if (lane >= off) sv += o;
  }
  if (lane==63) ds[wid] = sv;
  __syncthreads();
  if (tid < 64){
    double w = (tid<4)? ds[tid] : 0.0;
    for (int off=1; off<4; off<<=1){
      double o = __shfl_up(w, off);
      if (tid >= off) w += o;
    }
    if (tid<4) ds[tid] = w;
  }
  __syncthreads();
  double add = (wid>0)? ds[wid-1] : 0.0;
  return sv + add;
}

// Fused: bucket histogram + P counts + D-table fill (4 phase-shifted copies).
__global__ void k_hist(const float* __restrict__ scores, const int* __restrict__ labels,
                       int B, int NC, u32* __restrict__ bhist, u32* __restrict__ Pcnt,
                       float* __restrict__ Dsh, int SD){
  int t = blockIdx.x*256 + threadIdx.x;
  if (t < 4*SD){
    int p = t / SD, y = t - p*SD;
    long long x = (long long)y + p;
    Dsh[t] = (x==0) ? 0.0f : (float)(1.0/log2(1.0 + (double)x));
  }
  if (t >= B*NC) return;
  int b = t / NC, c = t - (t/NC)*NC;
  float v = scores[t];
  int isPos = (labels[b] == c);
  u32 u = f2key(v);
  u32 bucket = u >> BSHIFT;
  int pi = c*2 + (isPos ? 0 : 1);   // part0=pos, part1=neg
  atomicAdd(&bhist[(size_t)pi*NBUCKET + bucket], 1u);
  if (isPos) atomicAdd(&Pcnt[c], 1u);
}

// Exclusive scan of 16384 bins per (class,part); 16 bins/thread; shfl scan.
__global__ void k_scan(const u32* __restrict__ bhist, u32* __restrict__ bstart, u32* __restrict__ bcursor){
  __shared__ u32 ws[17];
  int pi = blockIdx.x, tid = threadIdx.x;
  const u32* h = bhist + (size_t)pi*NBUCKET;
  u32 v[16]; u32 tot = 0u;
  #pragma unroll
  for (int k=0;k<16;k++){ v[k] = h[tid*16+k]; tot += v[k]; }
  u32 incl = blk_scan_incl_u32(tot, tid, ws);
  u32 run = incl - tot;  // exclusive prefix for this thread's 16 bins
  u32* bs = bstart  + (size_t)pi*(NBUCKET+1);
  u32* bc = bcursor + (size_t)pi*NBUCKET;
  #pragma unroll
  for (int k=0;k<16;k++){ bs[tid*16+k]=run; bc[tid*16+k]=run; run+=v[k]; }
  if (tid==1023) bs[NBUCKET]=incl;
}

// Scatter packed keys (key<<32 | orig_index) into bucket-grouped order.
__global__ void k_scatter(const float* __restrict__ scores, const int* __restrict__ labels,
                          int B, int NC, u32* __restrict__ bcursor, u64* __restrict__ keyArr){
  int t = blockIdx.x*256 + threadIdx.x;
  if (t >= B*NC) return;
  int b = t / NC, c = t - (t/NC)*NC;
  float v = scores[t];
  int isPos = (labels[b] == c);
  u32 u = f2key(v);
  u32 bucket = u >> BSHIFT;
  int pi = c*2 + (isPos ? 0 : 1);
  u32 slot = atomicAdd(&bcursor[(size_t)pi*NBUCKET + bucket], 1u);
  keyArr[(size_t)pi*B + slot] = ((u64)u << 32) | (u32)b;
}

// Exact rank within bucket (deterministic via unique packed keys) -> sorted arrays.
__global__ void k_rank(const u64* __restrict__ keyArr, const u32* __restrict__ bstart,
                       const u32* __restrict__ Pcnt, int B,
                       float* __restrict__ sPos, float* __restrict__ sNeg){
  int pi = blockIdx.y; int c = pi >> 1; int part = pi & 1;
  u32 P = Pcnt[c];
  u32 cnt = part ? ((u32)B - P) : P;
  u32 t = blockIdx.x*256 + threadIdx.x;
  if (t >= cnt) return;
  const u64* ka = keyArr + (size_t)pi*B;
  u64 K = ka[t];
  u32 bucket = (u32)(K >> (32 + BSHIFT));
  const u32* bs = bstart + (size_t)pi*(NBUCKET+1);
  u32 lo = bs[bucket], hi = bs[bucket+1];
  u32 r = lo;
  for (u32 x=lo; x<hi; ++x) r += (ka[x] < K) ? 1u : 0u;
  u32 u = (u32)(K >> 32);
  u32 bits = (u & 0x80000000u) ? (u & 0x7fffffffu) : ~u;
  float val = __uint_as_float(bits);
  if (part == 0) sPos[(size_t)c*B + (P-1u-r)] = val;   // descending
  else           sNeg[(size_t)c*B + r]        = val;   // ascending
}

// Brute-force argmax, self-contained: each block computes A'/B' into LDS from
// sPos (shfl reduce + chunked shfl scan), then runs the vectorized stride-4
// scan with a group-of-4 max tree (leftmost-exact: strict > keeps first group;
// winning group resolved to leftmost-equal element at chunk end).
__global__ void k_main(const float* __restrict__ sNeg, const float* __restrict__ sPos,
                       const u32* __restrict__ Pcnt,
                       const float* __restrict__ Dsh, int SD, int B,
                       u32* __restrict__ optArr, double* __restrict__ partials){
  __shared__ float sA[CHK], sB[CHK];
  __shared__ double ds[5];
  __shared__ double l1[4], l2[4];
  int c = blockIdx.y;
  u32 P = Pcnt[c]; u32 N = (u32)B - P;
  int tid  = threadIdx.x;
  int w    = tid >> 6;
  int lane = tid & 63;
  int m = blockIdx.x*256 + w + 4*lane;       // stride-4 mapping (R9, proven)
  const float* sp = sPos + (size_t)c*B;
  const float* sn = sNeg + (size_t)c*B;
  bool classValid = (P>0u && N>0u);
  bool blockActive = classValid && (blockIdx.x*256 < (int)N);
  double s1=0.0, s2=0.0;

  if (blockActive){
    int total = (int)P + 1;
    // Cc, totSp (block-wide, doubles)
    double s=0.0;
    for (u32 i=1+tid; i<=P; i+=256) s += (double)Dsh[i];   // copy 0 = plain D
    double Cc = blk4_reduce_d(s, tid, ds);
    double ts=0.0;
    for (u32 i=tid; i<P; i+=256) ts += (double)sp[i];
    double totSp = blk4_reduce_d(ts, tid, ds);
    double PN = (double)P*(double)N;
    double ca = -2.0*Cc/PN, cb = 2.0*Cc/PN;

    bool mValid = (m < (int)N);
    float sm = mValid ? sn[m] : 0.0f;
    int ph = (m+1) & 3;                                // wave-uniform
    const float* Dp = Dsh + (size_t)ph*SD + (m+1-ph);  // Dp[j]=D(m+1+j), j%4==0 aligned

    float best = -3.402823466e38f;
    u32 bj = 0u;
    int bgrp = -1;                 // pending winning group base (absolute j)
    double carry = 0.0;            // prefix sum of sp up to current chunk start

    for (int j0 = 0; j0 < total; j0 += CHK){
      int j1 = min(j0 + CHK, total);
      int len = j1 - j0;
      // ---- cooperative fill of sA/sB for j in [j0, j1) ----
      for (int i0 = 0; i0 < len; i0 += 256){
        int i = i0 + tid;
        int x = j0 + i;
        double v = (i < len && x < (int)P) ? (double)sp[x] : 0.0;
        double incl = blk4_scan_incl_d(v, tid, ds);
        if (i < len){
          if (x == (int)P){ sA[i] = 0.0f; sB[i] = 0.0f; }   // match k_pre exactly
          else {
            double excl = incl - v + carry;   // sum sp[0..x-1]
            double Sl = totSp - excl;         // sum_{k=x}^{P-1} sp[k]
            sA[i] = (float)(ca*Sl);
            sB[i] = (float)(cb*(double)((int)P - x));
          }
        }
        carry += ds[3];                       // chunk-part total
        __syncthreads();                      // protect ds + sA/sB coherence
      }
      // ---- per-thread scan of this chunk ----
      if (mValid){
        int lenv = len & ~3;
        int i = 0;
        #pragma unroll 2
        for (; i < lenv; i += 4){
          float4 a = *(const float4*)(sA + i);
          float4 b = *(const float4*)(sB + i);
          float4 d = *(const float4*)(Dp + j0 + i);
          float f0 = fmaf(b.x, sm, a.x) + d.x;
          float f1 = fmaf(b.y, sm, a.y) + d.y;
          float f2 = fmaf(b.z, sm, a.z) + d.z;
          float f3 = fmaf(b.w, sm, a.w) + d.w;
          float g = fmaxf(fmaxf(f0,f1), fmaxf(f2,f3));
          if (g > best){ best = g; bgrp = j0 + i; }   // first group wins ties
        }
        for (; i < len; ++i){                          // scalar tail (last chunk)
          float f = fmaf(sB[i], sm, sA[i]) + Dp[j0 + i];
          if (f > best){ best = f; bj = (u32)(j0 + i); bgrp = -2; }
        }
        // resolve pending group while sA/sB still valid (leftmost == best)
        if (bgrp >= j0){
          int i2 = bgrp - j0;
          float4 a = *(const float4*)(sA + i2);
          float4 b = *(const float4*)(sB + i2);
          float4 d = *(const float4*)(Dp + bgrp);
          float f0 = fmaf(b.x, sm, a.x) + d.x;
          float f1 = fmaf(b.y, sm, a.y) + d.y;
          float f2 = fmaf(b.z, sm, a.z) + d.z;
          float f3 = fmaf(b.w, sm, a.w) + d.w;
          u32 o = (f0==best) ? 0u : (f1==best) ? 1u : (f2==best) ? 2u : 3u;
          bj = (u32)bgrp + o;
          bgrp = -1;
        }
      }
      __syncthreads();               // before next chunk's refill
    }
    if (mValid){
      u32 opt = bj + 1u;
      optArr[(size_t)c*B + m] = opt;           // plain coalesced store
      s1 = (double)sm;
      s2 = (double)sm * (double)opt;
    }
  }
  for (int off=32; off>0; off>>=1){
    s1 += __shfl_down(s1, off);
    s2 += __shfl_down(s2, off);
  }
  if (lane==0){ l1[w]=s1; l2[w]=s2; }
  __syncthreads();
  if (tid==0){
    double* p = partials + ((size_t)c*gridDim.x + blockIdx.x)*2;
    p[0] = l1[0]+l1[1]+l1[2]+l1[3];
    p[1] = l2[0]+l2[1]+l2[2]+l2[3];
  }
}

// Per-class finish: computes Cconst itself; ORDER-AGNOSTIC r_plus via LDS
// histogram + shfl chunked scan; last-block-done writes out[0].
__global__ void k_finish(const float* __restrict__ sPos, const u32* __restrict__ Pcnt,
                         const u32* __restrict__ optArr, const float* __restrict__ Dsh,
                         const double* __restrict__ partials,
                         int B, int nblkM, int NC,
                         u64* __restrict__ classLoss, u32* __restrict__ doneCount,
                         float* __restrict__ out){
  __shared__ u32 hbins[HBINS];
  __shared__ u32 ws[17];
  __shared__ double ds[17];
  int c = blockIdx.x, tid = threadIdx.x;
  u32 P = Pcnt[c]; u32 N = (u32)B - P;
  double myLoss = 0.0;
  if (P!=0 && N!=0){
    // Cconst = sum Dsh[1..P]
    double sC=0.0;
    for (u32 i=1+tid; i<=P; i+=1024) sC += (double)Dsh[i];
    double Cc = blk_reduce_d(sC, tid, ds);

    const u32* oa = optArr + (size_t)c*B;
    const float* sp = sPos + (size_t)c*B;
    double sumD=0.0, sumSpr=0.0, sumSp=0.0;
    if ((int)P + 2 <= HBINS){
      for (int i = tid; i < (int)P + 2; i += 1024) hbins[i] = 0u;
      __syncthreads();
      for (int m2 = tid; m2 < (int)N; m2 += 1024)
        atomicAdd(&hbins[oa[m2]], 1u);             // LDS atomic
      __syncthreads();
      u32 carry=0u;
      int nch = ((int)P + 1023)/1024;
      for (int ch=0; ch<nch; ++ch){
        int x = ch*1024 + tid;
        u32 v = (x < (int)P) ? hbins[x+1] : 0u;
        u32 incl = blk_scan_incl_u32(v, tid, ws);
        u32 cum = incl + carry;
        if (x < (int)P){
          u32 r = 1u + cum;
          float spv = sp[x];
          sumD   += (double)Dsh[x + r];
          sumSpr += (double)spv * (double)r;
          sumSp  += (double)spv;
        }
        carry += ws[15];                           // chunk total
        __syncthreads();
      }
    } else {
      for (int x = tid; x < (int)P; x += 1024){
        u32 target = (u32)x + 1u, cnt2 = 0u;
        for (u32 m2 = 0; m2 < N; ++m2) cnt2 += (oa[m2] <= target) ? 1u : 0u;
        u32 r = 1u + cnt2;
        float spv = sp[x];
        sumD   += (double)Dsh[x + r];
        sumSpr += (double)spv * (double)r;
        sumSp  += (double)spv;
      }
    }
    double totD   = blk_reduce_d(sumD,   tid, ds);
    double totSpr = blk_reduce_d(sumSpr, tid, ds);
    double totSp  = blk_reduce_d(sumSp,  tid, ds);
    if (tid==0){
      double S1=0.0, S2=0.0;
      const double* pp = partials + (size_t)c*nblkM*2;
      for (int b=0;b<nblkM;b++){ S1+=pp[2*b]; S2+=pp[2*b+1]; }
      double Delta = 1.0 - totD/Cc;
      double Fp    = (double)(N+2u)*totSp - 2.0*totSpr;   // sum s_plus*c_plus
      double Fm    = (double)(P+2u)*S1   - 2.0*S2;        // sum s_minus*c_minus
      double Fstar = (double)N*totSp - (double)P*S1;
      myLoss = Delta + (Fp + Fm - Fstar)/((double)P*(double)N);
    }
  }
  if (tid==0){
    atomicExch(&classLoss[c], (u64)__double_as_longlong(myLoss));
    __threadfence();
    u32 old = atomicAdd(doneCount, 1u);
    if (old == (u32)gridDim.x - 1u){
      __threadfence();
      double s=0.0;
      for (int cc=0; cc<NC; ++cc){
        u64 bits = atomicAdd(&classLoss[cc], 0ull);  // coherent read
        s += __longlong_as_double((long long)bits);
      }
      out[0] = (float)(s/(double)NC);
    }
  }
}

extern "C" void kernel_launch(void* const* d_in, const int* in_sizes, int n_in,
                              void* d_out, int out_size, void* d_ws, size_t ws_size,
                              hipStream_t stream) {
  const float* scores = (const float*)d_in[0];
  const int*   labels = (const int*)d_in[1];
  int B  = in_sizes[1];
  int NC = in_sizes[0] / in_sizes[1];
  float* out = (float*)d_out;

  int SD = B + 8;            // per-copy stride of shifted D tables
  int nblkM = (B + 255)/256; // k_main blocks per class

  char* ws = (char*)d_ws;
  size_t off = 0;
  auto alloc = [&](size_t bytes)->char* {
    char* p = ws + off;
    off = (off + bytes + 255) & ~(size_t)255;
    return p;
  };
  float* Dsh = (float*)alloc((size_t)4*SD*4);
  // ---- zeroed region (must stay contiguous) ----
  char* zbeg = ws + off;
  u32* bhist     = (u32*)alloc((size_t)NC*2*NBUCKET*4);
  u32* Pcnt      = (u32*)alloc((size_t)NC*4);
  u32* doneCount = (u32*)alloc(4);
  char* zend = ws + off;
  // ----------------------------------------------
  u32* bstart    = (u32*)alloc((size_t)NC*2*(NBUCKET+1)*4);
  u32* bcursor   = (u32*)alloc((size_t)NC*2*NBUCKET*4);
  u64* keyArr    = (u64*)alloc((size_t)NC*2*B*8);
  float* sPos    = (float*)alloc((size_t)NC*B*4);
  float* sNeg    = (float*)alloc((size_t)NC*B*4);
  u32* optArr    = (u32*)alloc((size_t)NC*B*4);
  double* partials  = (double*)alloc((size_t)NC*nblkM*2*8);
  u64* classLoss    = (u64*)alloc((size_t)NC*8);

  hipMemsetAsync(zbeg, 0, (size_t)(zend - zbeg), stream);

  k_hist<<<(B*NC+255)/256, 256, 0, stream>>>(scores, labels, B, NC, bhist, Pcnt, Dsh, SD);
  k_scan<<<NC*2, 1024, 0, stream>>>(bhist, bstart, bcursor);
  k_scatter<<<(B*NC+255)/256, 256, 0, stream>>>(scores, labels, B, NC, bcursor, keyArr);
  k_rank<<<dim3((B+255)/256, NC*2), 256, 0, stream>>>(keyArr, bstart, Pcnt, B, sPos, sNeg);
  k_main<<<dim3(nblkM, NC), 256, 0, stream>>>(sNeg, sPos, Pcnt, Dsh, SD, B, optArr, partials);
  k_finish<<<NC, 1024, 0, stream>>>(sPos, Pcnt, optArr, Dsh, partials, B, nblkM, NC,
                                    classLoss, doneCount, out);
}